// Round 11
// baseline (115.783 us; speedup 1.0000x reference)
//
#include <hip/hip_runtime.h>

typedef unsigned short u16;
typedef __attribute__((ext_vector_type(4))) unsigned short u16x4;
typedef __attribute__((ext_vector_type(8))) short s8v;
typedef __attribute__((ext_vector_type(4))) float f4v;

#define BB 4
#define SS 1024
#define EE 768
#define HH 12
#define DD 64

#define NHS (BB * SS * EE)           // 3145728
#define NW  (EE * EE)                // 589824
#define LOG2E 1.4426950408889634f
#define NBH (BB * HH)                // 48

static __device__ __forceinline__ u16 f2bf(float x){
  unsigned int u = __float_as_uint(x);
  u += 0x7fffu + ((u >> 16) & 1u);
  return (u16)(u >> 16);
}
static __device__ __forceinline__ unsigned cvt_pk_bf16(float lo, float hi){
  unsigned r;
  asm("v_cvt_pk_bf16_f32 %0, %1, %2" : "=v"(r) : "v"(lo), "v"(hi));
  return r;
}
// async global->LDS, 16B per lane; lds base must be wave-uniform
static __device__ __forceinline__ void stage16(const u16* g, u16* l){
  __builtin_amdgcn_global_load_lds(
      (const __attribute__((address_space(1))) void*)g,
      (__attribute__((address_space(3))) void*)l, 16, 0, 0);
}

// ---------------- fused prep: cvt (swizzled bf16) + tbl + gate ----------------
// blocks [0,2688): cvt; [2688,2784): tbl; [2784,15072): gate
__global__ __launch_bounds__(256) void prep_kernel(const float* __restrict__ hs,
                                                   const float* __restrict__ qw,
                                                   const float* __restrict__ kw,
                                                   const float* __restrict__ vw,
                                                   const float* __restrict__ ow,
                                                   u16* __restrict__ dst,
                                                   const float* __restrict__ rel_embed,
                                                   float* __restrict__ tbl,
                                                   const float* __restrict__ gru_w,
                                                   const float* __restrict__ gru_b,
                                                   const float* __restrict__ gru_c,
                                                   float* __restrict__ gate){
  const int bid = blockIdx.x;
  if (bid < 2688){
    // ---- cvt: f32 -> bf16, swizzled k ^ ((row&7)<<3) ----
    size_t e = ((size_t)bid * 256 + threadIdx.x) * 8;
    const float* src;
    if      (e < (size_t)NHS)            src = hs + e;
    else if (e < (size_t)NHS + NW)       src = qw + (e - NHS);
    else if (e < (size_t)NHS + 2 * NW)   src = kw + (e - NHS - NW);
    else if (e < (size_t)NHS + 3 * NW)   src = vw + (e - NHS - 2 * (size_t)NW);
    else                                 src = ow + (e - NHS - 3 * (size_t)NW);
    f4v v0 = *(const f4v*)src, v1 = *(const f4v*)(src + 4);
    s8v o;
    #pragma unroll
    for (int i = 0; i < 4; i++){ o[i] = (short)f2bf(v0[i]); o[4 + i] = (short)f2bf(v1[i]); }
    size_t row = e / EE;
    int k = (int)(e - row * EE);
    size_t d = row * EE + (size_t)(k ^ (((int)row & 7) << 3));
    *(s8v*)(dst + d) = o;
  } else if (bid < 2784){
    // ---- tbl: 1-D bias table tbl[h][rel+1023], stride 2048 ----
    int id = (bid - 2688) * 256 + threadIdx.x;   // over 12*2048
    int h = id >> 11, r = id & 2047;
    float v = 0.f;
    if (r < 2047){
      int rel = r - 1023;
      int bucket = (rel > 0) ? 160 : 0;
      int a = rel < 0 ? -rel : rel;
      int idx;
      if (a < 80) idx = a;
      else {
        float t = logf((float)a / 80.0f);
        t = t / 2.302585092994046f * 80.0f;
        int lg = (int)(80.0f + t);
        idx = lg < 159 ? lg : 159;
      }
      v = rel_embed[(idx + bucket) * HH + h];
    }
    tbl[id] = v;
  } else {
    // ---- gate ----
    int wid = (bid - 2784) * 4 + (threadIdx.x >> 6);  // over B*H*S rows
    int lane = threadIdx.x & 63;
    int s = wid & (SS - 1);
    int bh = wid >> 10;
    int h = bh % HH, b = bh / HH;
    float x = hs[(size_t)(b * SS + s) * EE + h * DD + lane];
    float w0 = gru_w[lane] + gru_w[64 + lane] + gru_w[128 + lane] + gru_w[192 + lane];
    float w1 = gru_w[256 + lane] + gru_w[320 + lane] + gru_w[384 + lane] + gru_w[448 + lane];
    float y0 = x * w0, y1 = x * w1;
    #pragma unroll
    for (int off = 1; off < 64; off <<= 1){
      y0 += __shfl_xor(y0, off);
      y1 += __shfl_xor(y1, off);
    }
    if (lane == 0){
      float s0 = y0 + gru_b[0] + gru_b[1] + gru_b[2] + gru_b[3];
      float s1 = y1 + gru_b[4] + gru_b[5] + gru_b[6] + gru_b[7];
      float ga = 1.f / (1.f + __expf(-s0));
      float gb = 1.f / (1.f + __expf(-s1));
      gate[wid] = ga * (gb * gru_c[h] - 1.0f) + 2.0f;
    }
  }
}

// ---------------- bf16 NT GEMM: 128x128 tile, BK=64, global_load_lds staging ----------------
// A and Bw are stored SWIZZLED (k ^ ((row&7)<<3)); LDS is linear [128][64].
// EP: 0 = pack16 (Q/K fragment-major), 1 = f32 row-major, 2 = vpack (PV B-operand)
template<int EP>
static __device__ __forceinline__ void gemm_body(const u16* __restrict__ A,
                                                 const u16* __restrict__ Bw,
                                                 const float* __restrict__ bias,
                                                 void* __restrict__ Cp,
                                                 float scale, int m0, int n0){
  __shared__ __align__(16) u16 a_s[128 * 64];
  __shared__ __align__(16) u16 b_s[128 * 64];
  const int t = threadIdx.x;
  const int wave = t >> 6, lane = t & 63;
  const int lr = lane & 15, lg = lane >> 4;
  const int wm = (wave >> 1) * 64, wn = (wave & 1) * 64;
  const int srow = lane >> 3;            // 0..7 row-within-8 for staging
  const int scol = (lane & 7) * 8;       // element col within BK
  const int swz = (lr & 7) << 3;         // fragment-read XOR (elements)

  const f4v zero = {0.f, 0.f, 0.f, 0.f};
  f4v acc[4][4];
  #pragma unroll
  for (int i = 0; i < 4; i++)
    #pragma unroll
    for (int j = 0; j < 4; j++) acc[i][j] = zero;

  for (int k0 = 0; k0 < EE; k0 += 64){
    if (k0) __syncthreads();             // all waves done reading LDS
    #pragma unroll
    for (int i = 0; i < 4; i++){
      const int chunk = i * 4 + wave;    // 0..15, covers rows chunk*8..+8
      const int r = chunk * 8 + srow;
      stage16(A  + (size_t)(m0 + r) * EE + k0 + scol, &a_s[chunk * 512]);
      stage16(Bw + (size_t)(n0 + r) * EE + k0 + scol, &b_s[chunk * 512]);
    }
    __syncthreads();                     // DMA drained (vmcnt0) + data visible
    #pragma unroll
    for (int kk = 0; kk < 2; kk++){
      const int cbase = (kk * 32 + lg * 8) ^ swz;
      s8v af[4], bf[4];
      #pragma unroll
      for (int i = 0; i < 4; i++){
        af[i] = *(const s8v*)&a_s[(wm + i * 16 + lr) * 64 + cbase];
        bf[i] = *(const s8v*)&b_s[(wn + i * 16 + lr) * 64 + cbase];
      }
      #pragma unroll
      for (int i = 0; i < 4; i++)
        #pragma unroll
        for (int j = 0; j < 4; j++)
          acc[i][j] = __builtin_amdgcn_mfma_f32_16x16x32_bf16(af[i], bf[j], acc[i][j], 0, 0, 0);
    }
  }

  #pragma unroll
  for (int ii = 0; ii < 4; ii++){
    const int row0 = m0 + wm + ii * 16 + lg * 4;
    const int bb = row0 >> 10;               // batch
    const int s0 = row0 & (SS - 1);          // sequence index
    #pragma unroll
    for (int j = 0; j < 4; j++){
      const int col = n0 + wn + j * 16 + lr;
      const float bv = bias[col];
      if (EP == 0){
        const int h = col >> 6, dim = col & 63;
        const int bh = bb * HH + h;
        u16* dst = (u16*)Cp + ((size_t)((bh * 64 + (s0 >> 4)) * 2 + (dim >> 5))) * 512
                   + ((dim >> 3) & 3) * 128 + (s0 & 15) * 8 + (dim & 7);
        #pragma unroll
        for (int r = 0; r < 4; r++)
          dst[r * 8] = f2bf((acc[ii][j][r] + bv) * scale);
      } else if (EP == 2){
        const int h = col >> 6, dim = col & 63;
        const int bh = bb * HH + h;
        u16x4 pk;
        #pragma unroll
        for (int r = 0; r < 4; r++) pk[r] = f2bf(acc[ii][j][r] + bv);
        *(u16x4*)((u16*)Cp + ((size_t)(((bh * 16 + (s0 >> 6)) * 2 + ((s0 >> 5) & 1)) * 4 + (dim >> 4))) * 512
                  + ((s0 >> 3) & 3) * 128 + (dim & 15) * 8 + (s0 & 7)) = pk;
      } else {
        #pragma unroll
        for (int r = 0; r < 4; r++)
          ((float*)Cp)[(size_t)(row0 + r) * EE + col] = acc[ii][j][r] + bv;
      }
    }
  }
}

// fused Q,K,V GEMM: z selects weight/bias/output/epilogue
__global__ __launch_bounds__(256) void gemm_qkv(const u16* __restrict__ A,
                                                const u16* __restrict__ wqkv,
                                                const float* __restrict__ bq,
                                                const float* __restrict__ bk,
                                                const float* __restrict__ bv,
                                                u16* __restrict__ qo,
                                                u16* __restrict__ ko,
                                                u16* __restrict__ vo){
  const int z = blockIdx.z;
  if (z == 2)
    gemm_body<2>(A, wqkv + 2 * (size_t)NW, bv, vo, 1.0f, blockIdx.x * 128, blockIdx.y * 128);
  else
    gemm_body<0>(A, wqkv + (size_t)z * NW, z ? bk : bq, z ? ko : qo,
                 z ? 1.0f : 0.125f * LOG2E, blockIdx.x * 128, blockIdx.y * 128);
}

__global__ __launch_bounds__(256) void gemm_out(const u16* __restrict__ A,
                                                const u16* __restrict__ Bw,
                                                const float* __restrict__ bias,
                                                float* __restrict__ Cp){
  gemm_body<1>(A, Bw, bias, Cp, 1.0f, blockIdx.x * 128, blockIdx.y * 128);
}

// ---------------- flash attention, split-K x2: partials (o,m,l) per half ----------------
__global__ __launch_bounds__(256, 6) void attn_kernel(const u16* __restrict__ qpack,
                                                      const u16* __restrict__ kpack,
                                                      const u16* __restrict__ vpack,
                                                      const float* __restrict__ gate,
                                                      const float* __restrict__ tbl,
                                                      float* __restrict__ opar,
                                                      float* __restrict__ mpar,
                                                      float* __restrict__ lpar,
                                                      float* __restrict__ pb){
  __shared__ __align__(16) float tbl_s[2048];
  __shared__ __align__(16) u16 p_s[4][16][72];    // per-wave P[q][k]
  const int t = threadIdx.x, wave = t >> 6, lane = t & 63;
  const int lr = lane & 15, lg = lane >> 4;
  const int qb = blockIdx.x >> 1, half = blockIdx.x & 1;
  const int h = blockIdx.y, b = blockIdx.z;
  const int bh = b * HH + h;
  const int q0w = qb * 64 + wave * 16;            // wave's q-base; lane owns q = q0w + lr
  {
    const float* th = tbl + h * 2048 + t * 8;
    *(f4v*)&tbl_s[t * 8]     = *(const f4v*)th;
    *(f4v*)&tbl_s[t * 8 + 4] = *(const f4v*)(th + 4);
  }
  // Q fragments: coalesced from qpack (B-operand of swapped QK)
  const u16* qp = qpack + ((size_t)(bh * 64 + qb * 4 + wave)) * 1024 + lane * 8;
  const s8v qf0 = *(const s8v*)qp;
  const s8v qf1 = *(const s8v*)(qp + 512);
  const float gt = gate[(size_t)bh * SS + q0w + lr] * LOG2E;   // per-lane q gate
  __syncthreads();   // tbl_s ready (only barrier in kernel)

  const u16* kp = kpack + (size_t)bh * 65536 + lane * 8;   // + (kt*4+n)*1024 (+512)
  const u16* vp = vpack + (size_t)bh * 65536 + lane * 8;   // + kt*4096 + d*512 (+2048)

  const f4v zero = {0.f, 0.f, 0.f, 0.f};
  f4v o[4];
  #pragma unroll
  for (int d = 0; d < 4; d++) o[d] = zero;
  float m = -1e30f, l = 0.f;
  const int tb_off = 1023 - q0w + lg * 4 - lr;   // tbl idx = kt*64 + n*16 + tb_off + r

  for (int it = 0; it < 8; it++){
    const int kt = half * 8 + it;
    // K fragments (coalesced 1KB wave loads, L1/L2-resident)
    s8v kf0[4], kf1[4];
    #pragma unroll
    for (int n = 0; n < 4; n++){
      const u16* kr = kp + (kt * 4 + n) * 1024;
      kf0[n] = *(const s8v*)kr;
      kf1[n] = *(const s8v*)(kr + 512);
    }
    // swapped QK^T: S[k][q], q = lr lane-local, k = n*16 + lg*4 + r
    f4v sf[4];
    __builtin_amdgcn_s_setprio(1);
    #pragma unroll
    for (int n = 0; n < 4; n++){
      f4v z = zero;
      z = __builtin_amdgcn_mfma_f32_16x16x32_bf16(kf0[n], qf0, z, 0, 0, 0);
      z = __builtin_amdgcn_mfma_f32_16x16x32_bf16(kf1[n], qf1, z, 0, 0, 0);
      sf[n] = z;
    }
    __builtin_amdgcn_s_setprio(0);
    // gated relative bias
    #pragma unroll
    for (int n = 0; n < 4; n++){
      const float* tp = &tbl_s[kt * 64 + n * 16 + tb_off];
      #pragma unroll
      for (int r = 0; r < 4; r++)
        sf[n][r] += gt * tp[r];
    }
    // defer-max online softmax (base-2 domain), per-lane state (q = lr)
    float lm = fmaxf(fmaxf(fmaxf(sf[0][0], sf[0][1]), fmaxf(sf[0][2], sf[0][3])),
                     fmaxf(fmaxf(sf[1][0], sf[1][1]), fmaxf(sf[1][2], sf[1][3])));
    lm = fmaxf(lm, fmaxf(fmaxf(fmaxf(sf[2][0], sf[2][1]), fmaxf(sf[2][2], sf[2][3])),
                         fmaxf(fmaxf(sf[3][0], sf[3][1]), fmaxf(sf[3][2], sf[3][3]))));
    if (__any(lm - m > 8.0f)){
      float gm = fmaxf(lm, __shfl_xor(lm, 16));
      gm = fmaxf(gm, __shfl_xor(gm, 32));           // lanes with same lr agree
      float nm = fmaxf(m, gm);
      float sc = exp2f(m - nm);
      m = nm;
      l *= sc;
      float scq[4];
      #pragma unroll
      for (int r = 0; r < 4; r++) scq[r] = __shfl(sc, lg * 4 + r);
      #pragma unroll
      for (int d = 0; d < 4; d++)
        #pragma unroll
        for (int r = 0; r < 4; r++) o[d][r] *= scq[r];
    }
    float ps = 0.f;
    #pragma unroll
    for (int n = 0; n < 4; n++){
      #pragma unroll
      for (int r = 0; r < 4; r++){
        float p = exp2f(sf[n][r] - m);
        sf[n][r] = p;
        ps += p;
      }
    }
    l += ps;
    // pack P[k][q] -> p_s[q][k]
    #pragma unroll
    for (int n = 0; n < 4; n++){
      unsigned pk0 = cvt_pk_bf16(sf[n][0], sf[n][1]);
      unsigned pk1 = cvt_pk_bf16(sf[n][2], sf[n][3]);
      u16* prow = &p_s[wave][lr][n * 16 + lg * 4];
      *(unsigned*)prow       = pk0;
      *(unsigned*)(prow + 2) = pk1;
    }
    // V fragments (issued late to bound VGPR live range; TLP hides latency)
    s8v vf0[4], vf1[4];
    #pragma unroll
    for (int d = 0; d < 4; d++){
      const u16* vr = vp + kt * 4096 + d * 512;
      vf0[d] = *(const s8v*)vr;
      vf1[d] = *(const s8v*)(vr + 2048);
    }
    const s8v pf0 = *(const s8v*)&p_s[wave][lr][lg * 8];
    const s8v pf1 = *(const s8v*)&p_s[wave][lr][32 + lg * 8];
    __builtin_amdgcn_s_setprio(1);
    #pragma unroll
    for (int d = 0; d < 4; d++){
      o[d] = __builtin_amdgcn_mfma_f32_16x16x32_bf16(pf0, vf0[d], o[d], 0, 0, 0);
      o[d] = __builtin_amdgcn_mfma_f32_16x16x32_bf16(pf1, vf1[d], o[d], 0, 0, 0);
    }
    __builtin_amdgcn_s_setprio(0);
  }
  // partial l per q = lr (sum over this half's keys)
  l += __shfl_xor(l, 16);
  l += __shfl_xor(l, 32);
  if (lg == 0){
    mpar[(size_t)(half * NBH + bh) * SS + q0w + lr] = m;
    lpar[(size_t)(half * NBH + bh) * SS + q0w + lr] = l;
  }
  // partial o: opar[(half*NBH+bh)*SS + q][64]
  float* op = opar + ((size_t)(half * NBH + bh) * SS) * 64;
  #pragma unroll
  for (int d = 0; d < 4; d++)
    #pragma unroll
    for (int r = 0; r < 4; r++)
      op[(size_t)(q0w + lg * 4 + r) * 64 + d * 16 + lr] = o[d][r];
  // ---- fused position-bias (output 1): half-0 blocks own pb[h][i0..i0+15][:] ----
  if (half == 0){
    float* pbh = pb + (size_t)h * (SS * SS);
    const int i0 = (qb * 4 + b) * 16;
    #pragma unroll 4
    for (int rr = 0; rr < 16; rr++){
      const int i = i0 + rr;
      const int base = 1023 - i + t * 4;
      f4v v;
      v[0] = tbl_s[base + 0];
      v[1] = tbl_s[base + 1];
      v[2] = tbl_s[base + 2];
      v[3] = tbl_s[base + 3];
      __builtin_nontemporal_store(v, (f4v*)&pbh[(size_t)i * SS + t * 4]);
    }
  }
}

// ---------------- split-K combine: merge halves, write swizzled bf16 ctx ----------------
__global__ __launch_bounds__(256) void combine_kernel(const float* __restrict__ opar,
                                                      const float* __restrict__ mpar,
                                                      const float* __restrict__ lpar,
                                                      u16* __restrict__ ctx){
  const int qb = blockIdx.x, h = blockIdx.y, b = blockIdx.z;
  const int bh = b * HH + h;
  const int t = threadIdx.x;
  const int ql = t >> 2, d0 = (t & 3) * 16;
  const int q = qb * 64 + ql;
  const size_t i0 = (size_t)bh * SS + q;
  const size_t i1 = (size_t)(NBH * SS) + i0;
  float m0 = mpar[i0], m1 = mpar[i1];
  float l0 = lpar[i0], l1 = lpar[i1];
  float M = fmaxf(m0, m1);
  float w0 = exp2f(m0 - M), w1 = exp2f(m1 - M);
  float rL = 1.0f / (l0 * w0 + l1 * w1);
  w0 *= rL; w1 *= rL;
  const float* o0p = opar + i0 * 64 + d0;
  const float* o1p = opar + i1 * 64 + d0;
  u16* crow = ctx + (size_t)(b * SS + q) * EE;
  const int cswz = (q & 7) << 3;
  #pragma unroll
  for (int c = 0; c < 4; c++){
    f4v a = *(const f4v*)(o0p + c * 4);
    f4v bb = *(const f4v*)(o1p + c * 4);
    #pragma unroll
    for (int j = 0; j < 4; j++){
      const int dd = d0 + c * 4 + j;
      crow[(h * DD + dd) ^ cswz] = f2bf(a[j] * w0 + bb[j] * w1);
    }
  }
}

extern "C" void kernel_launch(void* const* d_in, const int* in_sizes, int n_in,
                              void* d_out, int out_size, void* d_ws, size_t ws_size,
                              hipStream_t stream){
  const float* hs    = (const float*)d_in[0];
  const float* q_w   = (const float*)d_in[1];
  const float* q_b   = (const float*)d_in[2];
  const float* k_w   = (const float*)d_in[3];
  const float* k_b   = (const float*)d_in[4];
  const float* v_w   = (const float*)d_in[5];
  const float* v_b   = (const float*)d_in[6];
  const float* o_w   = (const float*)d_in[7];
  const float* o_b   = (const float*)d_in[8];
  const float* gru_c = (const float*)d_in[9];
  const float* gru_w = (const float*)d_in[10];
  const float* gru_b = (const float*)d_in[11];
  const float* rel   = (const float*)d_in[12];

  float* out0 = (float*)d_out;
  float* pb   = out0 + (size_t)BB * SS * EE;

  char* w = (char*)d_ws;
  u16* qpk  = (u16*)w;  w += (size_t)NHS * 2;
  u16* kpk  = (u16*)w;  w += (size_t)NHS * 2;
  u16* vpk  = (u16*)w;  w += (size_t)NHS * 2;
  u16* cvt  = (u16*)w;  w += ((size_t)NHS + 4 * (size_t)NW) * 2;
  float* gate = (float*)w; w += (size_t)BB * HH * SS * 4;
  float* tbl  = (float*)w; w += (size_t)HH * 2048 * 4;
  float* opar = (float*)w; w += (size_t)2 * NBH * SS * 64 * 4;   // 25.2 MB
  float* mpar = (float*)w; w += (size_t)2 * NBH * SS * 4;
  float* lpar = (float*)w;

  u16* hs_bf  = cvt;                   // swizzled; later reused as ctx (dead after GEMMs)
  u16* wqkv   = cvt + NHS;             // q_w, k_w, v_w bf16 packed, swizzled
  u16* ow_bf  = cvt + NHS + 3 * (size_t)NW;

  prep_kernel<<<15072, 256, 0, stream>>>(hs, q_w, k_w, v_w, o_w, cvt,
                                         rel, tbl, gru_w, gru_b, gru_c, gate);
  gemm_qkv<<<dim3(32, 6, 3), 256, 0, stream>>>(hs_bf, wqkv, q_b, k_b, v_b, qpk, kpk, vpk);
  attn_kernel<<<dim3(32, HH, BB), 256, 0, stream>>>(qpk, kpk, vpk, gate, tbl,
                                                    opar, mpar, lpar, pb);
  combine_kernel<<<dim3(16, HH, BB), 256, 0, stream>>>(opar, mpar, lpar, hs_bf);
  gemm_out<<<dim3(32, 6), 256, 0, stream>>>(hs_bf, ow_bf, o_b, out0);
}

// Round 12
// 100.880 us; speedup vs baseline: 1.1477x; 1.1477x over previous
//
#include <hip/hip_runtime.h>

typedef unsigned short u16;
typedef __attribute__((ext_vector_type(4))) unsigned short u16x4;
typedef __attribute__((ext_vector_type(8))) short s8v;
typedef __attribute__((ext_vector_type(4))) float f4v;

#define BB 4
#define SS 1024
#define EE 768
#define HH 12
#define DD 64

#define NHS (BB * SS * EE)           // 3145728
#define NW  (EE * EE)                // 589824
#define LOG2E 1.4426950408889634f

static __device__ __forceinline__ u16 f2bf(float x){
  unsigned int u = __float_as_uint(x);
  u += 0x7fffu + ((u >> 16) & 1u);
  return (u16)(u >> 16);
}
static __device__ __forceinline__ unsigned cvt_pk_bf16(float lo, float hi){
  unsigned r;
  asm("v_cvt_pk_bf16_f32 %0, %1, %2" : "=v"(r) : "v"(lo), "v"(hi));
  return r;
}
// async global->LDS, 16B per lane; lds base must be wave-uniform
static __device__ __forceinline__ void stage16(const u16* g, u16* l){
  __builtin_amdgcn_global_load_lds(
      (const __attribute__((address_space(1))) void*)g,
      (__attribute__((address_space(3))) void*)l, 16, 0, 0);
}

// ---------------- fused prep: cvt (swizzled bf16) + tbl + gate ----------------
// blocks [0,2688): cvt; [2688,2784): tbl; [2784,15072): gate
__global__ __launch_bounds__(256) void prep_kernel(const float* __restrict__ hs,
                                                   const float* __restrict__ qw,
                                                   const float* __restrict__ kw,
                                                   const float* __restrict__ vw,
                                                   const float* __restrict__ ow,
                                                   u16* __restrict__ dst,
                                                   const float* __restrict__ rel_embed,
                                                   float* __restrict__ tbl,
                                                   const float* __restrict__ gru_w,
                                                   const float* __restrict__ gru_b,
                                                   const float* __restrict__ gru_c,
                                                   float* __restrict__ gate){
  const int bid = blockIdx.x;
  if (bid < 2688){
    // ---- cvt: f32 -> bf16, swizzled k ^ ((row&7)<<3) ----
    size_t e = ((size_t)bid * 256 + threadIdx.x) * 8;
    const float* src;
    if      (e < (size_t)NHS)            src = hs + e;
    else if (e < (size_t)NHS + NW)       src = qw + (e - NHS);
    else if (e < (size_t)NHS + 2 * NW)   src = kw + (e - NHS - NW);
    else if (e < (size_t)NHS + 3 * NW)   src = vw + (e - NHS - 2 * (size_t)NW);
    else                                 src = ow + (e - NHS - 3 * (size_t)NW);
    f4v v0 = *(const f4v*)src, v1 = *(const f4v*)(src + 4);
    s8v o;
    #pragma unroll
    for (int i = 0; i < 4; i++){ o[i] = (short)f2bf(v0[i]); o[4 + i] = (short)f2bf(v1[i]); }
    size_t row = e / EE;
    int k = (int)(e - row * EE);
    size_t d = row * EE + (size_t)(k ^ (((int)row & 7) << 3));
    *(s8v*)(dst + d) = o;
  } else if (bid < 2784){
    // ---- tbl: 1-D bias table tbl[h][rel+1023], stride 2048 ----
    int id = (bid - 2688) * 256 + threadIdx.x;   // over 12*2048
    int h = id >> 11, r = id & 2047;
    float v = 0.f;
    if (r < 2047){
      int rel = r - 1023;
      int bucket = (rel > 0) ? 160 : 0;
      int a = rel < 0 ? -rel : rel;
      int idx;
      if (a < 80) idx = a;
      else {
        float t = logf((float)a / 80.0f);
        t = t / 2.302585092994046f * 80.0f;
        int lg = (int)(80.0f + t);
        idx = lg < 159 ? lg : 159;
      }
      v = rel_embed[(idx + bucket) * HH + h];
    }
    tbl[id] = v;
  } else {
    // ---- gate ----
    int wid = (bid - 2784) * 4 + (threadIdx.x >> 6);  // over B*H*S rows
    int lane = threadIdx.x & 63;
    int s = wid & (SS - 1);
    int bh = wid >> 10;
    int h = bh % HH, b = bh / HH;
    float x = hs[(size_t)(b * SS + s) * EE + h * DD + lane];
    float w0 = gru_w[lane] + gru_w[64 + lane] + gru_w[128 + lane] + gru_w[192 + lane];
    float w1 = gru_w[256 + lane] + gru_w[320 + lane] + gru_w[384 + lane] + gru_w[448 + lane];
    float y0 = x * w0, y1 = x * w1;
    #pragma unroll
    for (int off = 1; off < 64; off <<= 1){
      y0 += __shfl_xor(y0, off);
      y1 += __shfl_xor(y1, off);
    }
    if (lane == 0){
      float s0 = y0 + gru_b[0] + gru_b[1] + gru_b[2] + gru_b[3];
      float s1 = y1 + gru_b[4] + gru_b[5] + gru_b[6] + gru_b[7];
      float ga = 1.f / (1.f + __expf(-s0));
      float gb = 1.f / (1.f + __expf(-s1));
      gate[wid] = ga * (gb * gru_c[h] - 1.0f) + 2.0f;
    }
  }
}

// ---------------- bf16 NT GEMM: 128x128 tile, BK=64, global_load_lds staging ----------------
// A and Bw are stored SWIZZLED (k ^ ((row&7)<<3)); LDS is linear [128][64].
// EP: 0 = pack16 (Q/K fragment-major), 1 = f32 row-major, 2 = vpack (PV B-operand)
template<int EP>
static __device__ __forceinline__ void gemm_body(const u16* __restrict__ A,
                                                 const u16* __restrict__ Bw,
                                                 const float* __restrict__ bias,
                                                 void* __restrict__ Cp,
                                                 float scale, int m0, int n0){
  __shared__ __align__(16) u16 a_s[128 * 64];
  __shared__ __align__(16) u16 b_s[128 * 64];
  const int t = threadIdx.x;
  const int wave = t >> 6, lane = t & 63;
  const int lr = lane & 15, lg = lane >> 4;
  const int wm = (wave >> 1) * 64, wn = (wave & 1) * 64;
  const int srow = lane >> 3;            // 0..7 row-within-8 for staging
  const int scol = (lane & 7) * 8;       // element col within BK
  const int swz = (lr & 7) << 3;         // fragment-read XOR (elements)

  const f4v zero = {0.f, 0.f, 0.f, 0.f};
  f4v acc[4][4];
  #pragma unroll
  for (int i = 0; i < 4; i++)
    #pragma unroll
    for (int j = 0; j < 4; j++) acc[i][j] = zero;

  for (int k0 = 0; k0 < EE; k0 += 64){
    if (k0) __syncthreads();             // all waves done reading LDS
    #pragma unroll
    for (int i = 0; i < 4; i++){
      const int chunk = i * 4 + wave;    // 0..15, covers rows chunk*8..+8
      const int r = chunk * 8 + srow;
      stage16(A  + (size_t)(m0 + r) * EE + k0 + scol, &a_s[chunk * 512]);
      stage16(Bw + (size_t)(n0 + r) * EE + k0 + scol, &b_s[chunk * 512]);
    }
    __syncthreads();                     // DMA drained (vmcnt0) + data visible
    #pragma unroll
    for (int kk = 0; kk < 2; kk++){
      const int cbase = (kk * 32 + lg * 8) ^ swz;
      s8v af[4], bf[4];
      #pragma unroll
      for (int i = 0; i < 4; i++){
        af[i] = *(const s8v*)&a_s[(wm + i * 16 + lr) * 64 + cbase];
        bf[i] = *(const s8v*)&b_s[(wn + i * 16 + lr) * 64 + cbase];
      }
      #pragma unroll
      for (int i = 0; i < 4; i++)
        #pragma unroll
        for (int j = 0; j < 4; j++)
          acc[i][j] = __builtin_amdgcn_mfma_f32_16x16x32_bf16(af[i], bf[j], acc[i][j], 0, 0, 0);
    }
  }

  #pragma unroll
  for (int ii = 0; ii < 4; ii++){
    const int row0 = m0 + wm + ii * 16 + lg * 4;
    const int bb = row0 >> 10;               // batch
    const int s0 = row0 & (SS - 1);          // sequence index
    #pragma unroll
    for (int j = 0; j < 4; j++){
      const int col = n0 + wn + j * 16 + lr;
      const float bv = bias[col];
      if (EP == 0){
        const int h = col >> 6, dim = col & 63;
        const int bh = bb * HH + h;
        u16* dst = (u16*)Cp + ((size_t)((bh * 64 + (s0 >> 4)) * 2 + (dim >> 5))) * 512
                   + ((dim >> 3) & 3) * 128 + (s0 & 15) * 8 + (dim & 7);
        #pragma unroll
        for (int r = 0; r < 4; r++)
          dst[r * 8] = f2bf((acc[ii][j][r] + bv) * scale);
      } else if (EP == 2){
        const int h = col >> 6, dim = col & 63;
        const int bh = bb * HH + h;
        u16x4 pk;
        #pragma unroll
        for (int r = 0; r < 4; r++) pk[r] = f2bf(acc[ii][j][r] + bv);
        *(u16x4*)((u16*)Cp + ((size_t)(((bh * 16 + (s0 >> 6)) * 2 + ((s0 >> 5) & 1)) * 4 + (dim >> 4))) * 512
                  + ((s0 >> 3) & 3) * 128 + (dim & 15) * 8 + (s0 & 7)) = pk;
      } else {
        #pragma unroll
        for (int r = 0; r < 4; r++)
          ((float*)Cp)[(size_t)(row0 + r) * EE + col] = acc[ii][j][r] + bv;
      }
    }
  }
}

// fused Q,K,V GEMM: z selects weight/bias/output/epilogue
__global__ __launch_bounds__(256) void gemm_qkv(const u16* __restrict__ A,
                                                const u16* __restrict__ wqkv,
                                                const float* __restrict__ bq,
                                                const float* __restrict__ bk,
                                                const float* __restrict__ bv,
                                                u16* __restrict__ qo,
                                                u16* __restrict__ ko,
                                                u16* __restrict__ vo){
  const int z = blockIdx.z;
  if (z == 2)
    gemm_body<2>(A, wqkv + 2 * (size_t)NW, bv, vo, 1.0f, blockIdx.x * 128, blockIdx.y * 128);
  else
    gemm_body<0>(A, wqkv + (size_t)z * NW, z ? bk : bq, z ? ko : qo,
                 z ? 1.0f : 0.125f * LOG2E, blockIdx.x * 128, blockIdx.y * 128);
}

__global__ __launch_bounds__(256) void gemm_out(const u16* __restrict__ A,
                                                const u16* __restrict__ Bw,
                                                const float* __restrict__ bias,
                                                float* __restrict__ Cp){
  gemm_body<1>(A, Bw, bias, Cp, 1.0f, blockIdx.x * 128, blockIdx.y * 128);
}

// ---------------- flash attention: barrier-free, direct L2 loads, 2-tile ILP ----------------
// Flat 768-block grid with XCD-grouped remap: dispatch i -> XCD i%8 (round-robin),
// all 16 q-blocks of one (b,h) land on the same XCD -> K/V L2-resident per XCD.
__global__ __launch_bounds__(256) void attn_kernel(const u16* __restrict__ qpack,
                                                   const u16* __restrict__ kpack,
                                                   const u16* __restrict__ vpack,
                                                   const float* __restrict__ gate,
                                                   const float* __restrict__ tbl,
                                                   u16* __restrict__ ctx,
                                                   float* __restrict__ pb){
  __shared__ __align__(16) float tbl_s[2048];
  __shared__ __align__(16) u16 p_s[4][2][16][72];    // per-wave, per-tile P[q][k]
  const int t = threadIdx.x, wave = t >> 6, lane = t & 63;
  const int lr = lane & 15, lg = lane >> 4;
  // XCD-grouped remap (48 bh = 8 XCD x 6)
  const int i = blockIdx.x;
  const int xcd = i & 7, slot = i >> 3;
  const int bhg = xcd * 6 + (slot >> 4);     // 0..47
  const int qb  = slot & 15;                 // 0..15
  const int b = bhg / HH, h = bhg % HH;
  const int bh = bhg;
  const int q0w = qb * 64 + wave * 16;       // wave's q-base; lane owns q = q0w + lr
  {
    const float* th = tbl + h * 2048 + t * 8;
    *(f4v*)&tbl_s[t * 8]     = *(const f4v*)th;
    *(f4v*)&tbl_s[t * 8 + 4] = *(const f4v*)(th + 4);
  }
  // Q fragments: coalesced from qpack (B-operand of swapped QK)
  const u16* qp = qpack + ((size_t)(bh * 64 + qb * 4 + wave)) * 1024 + lane * 8;
  const s8v qf0 = *(const s8v*)qp;
  const s8v qf1 = *(const s8v*)(qp + 512);
  const float gt = gate[(size_t)bh * SS + q0w + lr] * LOG2E;   // per-lane q gate
  __syncthreads();   // tbl_s ready (only barrier in kernel)

  const u16* kp = kpack + (size_t)bh * 65536 + lane * 8;   // + (kt*4+n)*1024 (+512)
  const u16* vp = vpack + (size_t)bh * 65536 + lane * 8;   // + kt*4096 + d*512 (+2048)

  const f4v zero = {0.f, 0.f, 0.f, 0.f};
  f4v o[4];
  #pragma unroll
  for (int d = 0; d < 4; d++) o[d] = zero;
  float m = -1e30f, l = 0.f;
  const int tb_off = 1023 - q0w;       // tbl index = kt*64 + n*16 + tb_off + (lg*4 - lr) + r
  const int voff = lg * 4 - lr;

  for (int kt2 = 0; kt2 < 16; kt2 += 2){
    // K fragments, both tiles (32 coalesced 16B loads in flight)
    s8v kA0[4], kA1[4], kB0[4], kB1[4];
    #pragma unroll
    for (int n = 0; n < 4; n++){
      const u16* ka = kp + (kt2 * 4 + n) * 1024;
      const u16* kb = ka + 4096;
      kA0[n] = *(const s8v*)ka; kA1[n] = *(const s8v*)(ka + 512);
      kB0[n] = *(const s8v*)kb; kB1[n] = *(const s8v*)(kb + 512);
    }
    // swapped QK^T both tiles: S[k][q], q = lr lane-local
    f4v sA[4], sB[4];
    __builtin_amdgcn_s_setprio(1);
    #pragma unroll
    for (int n = 0; n < 4; n++){
      f4v z = zero;
      z = __builtin_amdgcn_mfma_f32_16x16x32_bf16(kA0[n], qf0, z, 0, 0, 0);
      z = __builtin_amdgcn_mfma_f32_16x16x32_bf16(kA1[n], qf1, z, 0, 0, 0);
      sA[n] = z;
      f4v z2 = zero;
      z2 = __builtin_amdgcn_mfma_f32_16x16x32_bf16(kB0[n], qf0, z2, 0, 0, 0);
      z2 = __builtin_amdgcn_mfma_f32_16x16x32_bf16(kB1[n], qf1, z2, 0, 0, 0);
      sB[n] = z2;
    }
    __builtin_amdgcn_s_setprio(0);
    // V loads issued here; latency hides under softmax below
    s8v vA0[4], vA1[4], vB0[4], vB1[4];
    #pragma unroll
    for (int d = 0; d < 4; d++){
      const u16* va = vp + kt2 * 4096 + d * 512;
      const u16* vb = va + 4096;
      vA0[d] = *(const s8v*)va; vA1[d] = *(const s8v*)(va + 2048);
      vB0[d] = *(const s8v*)vb; vB1[d] = *(const s8v*)(vb + 2048);
    }
    // gated relative bias
    #pragma unroll
    for (int n = 0; n < 4; n++){
      const float* tpA = &tbl_s[kt2 * 64 + n * 16 + tb_off + voff];
      #pragma unroll
      for (int r = 0; r < 4; r++){
        sA[n][r] += gt * tpA[r];
        sB[n][r] += gt * tpA[64 + r];
      }
    }
    // defer-max online softmax over the 128-key pair (base-2 domain), per-lane state
    float lmA = fmaxf(fmaxf(fmaxf(sA[0][0], sA[0][1]), fmaxf(sA[0][2], sA[0][3])),
                      fmaxf(fmaxf(sA[1][0], sA[1][1]), fmaxf(sA[1][2], sA[1][3])));
    lmA = fmaxf(lmA, fmaxf(fmaxf(fmaxf(sA[2][0], sA[2][1]), fmaxf(sA[2][2], sA[2][3])),
                           fmaxf(fmaxf(sA[3][0], sA[3][1]), fmaxf(sA[3][2], sA[3][3]))));
    float lmB = fmaxf(fmaxf(fmaxf(sB[0][0], sB[0][1]), fmaxf(sB[0][2], sB[0][3])),
                      fmaxf(fmaxf(sB[1][0], sB[1][1]), fmaxf(sB[1][2], sB[1][3])));
    lmB = fmaxf(lmB, fmaxf(fmaxf(fmaxf(sB[2][0], sB[2][1]), fmaxf(sB[2][2], sB[2][3])),
                           fmaxf(fmaxf(sB[3][0], sB[3][1]), fmaxf(sB[3][2], sB[3][3]))));
    float lm = fmaxf(lmA, lmB);
    if (__any(lm - m > 8.0f)){
      float gm = fmaxf(lm, __shfl_xor(lm, 16));
      gm = fmaxf(gm, __shfl_xor(gm, 32));           // all lanes with same lr agree
      float nm = fmaxf(m, gm);
      float sc = exp2f(m - nm);
      m = nm;
      l *= sc;
      float scq[4];
      #pragma unroll
      for (int r = 0; r < 4; r++) scq[r] = __shfl(sc, lg * 4 + r);
      #pragma unroll
      for (int d = 0; d < 4; d++)
        #pragma unroll
        for (int r = 0; r < 4; r++) o[d][r] *= scq[r];
    }
    float ps = 0.f;
    #pragma unroll
    for (int n = 0; n < 4; n++){
      #pragma unroll
      for (int r = 0; r < 4; r++){
        float pA = exp2f(sA[n][r] - m);
        float pB = exp2f(sB[n][r] - m);
        sA[n][r] = pA;
        sB[n][r] = pB;
        ps += pA + pB;
      }
    }
    l += ps;    // partial over this lane's k's; cross-lane reduce once at end
    // pack P[k][q] -> p_s[q][k], per-tile halves
    #pragma unroll
    for (int n = 0; n < 4; n++){
      unsigned a0 = cvt_pk_bf16(sA[n][0], sA[n][1]);
      unsigned a1 = cvt_pk_bf16(sA[n][2], sA[n][3]);
      unsigned b0 = cvt_pk_bf16(sB[n][0], sB[n][1]);
      unsigned b1 = cvt_pk_bf16(sB[n][2], sB[n][3]);
      u16* prowA = &p_s[wave][0][lr][n * 16 + lg * 4];
      u16* prowB = &p_s[wave][1][lr][n * 16 + lg * 4];
      *(unsigned*)prowA       = a0;
      *(unsigned*)(prowA + 2) = a1;
      *(unsigned*)prowB       = b0;
      *(unsigned*)(prowB + 2) = b1;
    }
    // per-wave LDS roundtrip (p_s[wave] private to wave; in-order LDS queue)
    const s8v pA0 = *(const s8v*)&p_s[wave][0][lr][lg * 8];
    const s8v pA1 = *(const s8v*)&p_s[wave][0][lr][32 + lg * 8];
    const s8v pB0 = *(const s8v*)&p_s[wave][1][lr][lg * 8];
    const s8v pB1 = *(const s8v*)&p_s[wave][1][lr][32 + lg * 8];
    __builtin_amdgcn_s_setprio(1);
    #pragma unroll
    for (int d = 0; d < 4; d++){
      o[d] = __builtin_amdgcn_mfma_f32_16x16x32_bf16(pA0, vA0[d], o[d], 0, 0, 0);
      o[d] = __builtin_amdgcn_mfma_f32_16x16x32_bf16(pA1, vA1[d], o[d], 0, 0, 0);
      o[d] = __builtin_amdgcn_mfma_f32_16x16x32_bf16(pB0, vB0[d], o[d], 0, 0, 0);
      o[d] = __builtin_amdgcn_mfma_f32_16x16x32_bf16(pB1, vB1[d], o[d], 0, 0, 0);
    }
    __builtin_amdgcn_s_setprio(0);
  }
  // finalize: full l per q = lr, then distribute 1/l to output rows q = lg*4 + r
  l += __shfl_xor(l, 16);
  l += __shfl_xor(l, 32);
  float rl = 1.0f / l;
  float linv[4];
  #pragma unroll
  for (int r = 0; r < 4; r++) linv[r] = __shfl(rl, lg * 4 + r);
  // ctx written in SWIZZLED layout (col ^ ((row&7)<<3)) for gemm_out's DMA staging
  #pragma unroll
  for (int d = 0; d < 4; d++)
    #pragma unroll
    for (int r = 0; r < 4; r++){
      float val = o[d][r] * linv[r];
      const int row = q0w + lg * 4 + r;
      const int col = (h * DD + d * 16 + lr) ^ ((row & 7) << 3);
      ctx[(size_t)(b * SS + row) * EE + col] = f2bf(val);
    }
  // ---- fused position-bias (output 1): this block owns pb[h][i0..i0+15][:] ----
  // tbl_s is complete and stable (written before first barrier, never overwritten)
  {
    float* pbh = pb + (size_t)h * (SS * SS);
    const int i0 = (qb * 4 + b) * 16;
    #pragma unroll 4
    for (int rr = 0; rr < 16; rr++){
      const int ii = i0 + rr;
      const int base = 1023 - ii + t * 4;
      f4v v;
      v[0] = tbl_s[base + 0];
      v[1] = tbl_s[base + 1];
      v[2] = tbl_s[base + 2];
      v[3] = tbl_s[base + 3];
      __builtin_nontemporal_store(v, (f4v*)&pbh[(size_t)ii * SS + t * 4]);
    }
  }
}

extern "C" void kernel_launch(void* const* d_in, const int* in_sizes, int n_in,
                              void* d_out, int out_size, void* d_ws, size_t ws_size,
                              hipStream_t stream){
  const float* hs    = (const float*)d_in[0];
  const float* q_w   = (const float*)d_in[1];
  const float* q_b   = (const float*)d_in[2];
  const float* k_w   = (const float*)d_in[3];
  const float* k_b   = (const float*)d_in[4];
  const float* v_w   = (const float*)d_in[5];
  const float* v_b   = (const float*)d_in[6];
  const float* o_w   = (const float*)d_in[7];
  const float* o_b   = (const float*)d_in[8];
  const float* gru_c = (const float*)d_in[9];
  const float* gru_w = (const float*)d_in[10];
  const float* gru_b = (const float*)d_in[11];
  const float* rel   = (const float*)d_in[12];

  float* out0 = (float*)d_out;
  float* pb   = out0 + (size_t)BB * SS * EE;

  char* w = (char*)d_ws;
  u16* qpk  = (u16*)w;  w += (size_t)NHS * 2;
  u16* kpk  = (u16*)w;  w += (size_t)NHS * 2;
  u16* vpk  = (u16*)w;  w += (size_t)NHS * 2;
  u16* cvt  = (u16*)w;  w += ((size_t)NHS + 4 * (size_t)NW) * 2;
  float* gate = (float*)w; w += (size_t)BB * HH * SS * 4;
  float* tbl  = (float*)w;

  u16* hs_bf  = cvt;                   // swizzled; later reused as ctx (dead after GEMMs)
  u16* wqkv   = cvt + NHS;             // q_w, k_w, v_w bf16 packed, swizzled
  u16* ow_bf  = cvt + NHS + 3 * (size_t)NW;

  prep_kernel<<<15072, 256, 0, stream>>>(hs, q_w, k_w, v_w, o_w, cvt,
                                         rel, tbl, gru_w, gru_b, gru_c, gate);
  gemm_qkv<<<dim3(32, 6, 3), 256, 0, stream>>>(hs_bf, wqkv, q_b, k_b, v_b, qpk, kpk, vpk);
  attn_kernel<<<768, 256, 0, stream>>>(qpk, kpk, vpk, gate, tbl, hs_bf, pb);
  gemm_out<<<dim3(32, 6), 256, 0, stream>>>(hs_bf, ow_bf, o_b, out0);
}